// Round 16
// baseline (82.384 us; speedup 1.0000x reference)
//
#include <hip/hip_runtime.h>
#include <hip/hip_bf16.h>
#include <math.h>

#define BH_ 32
#define N_ 4096
#define D_ 64
#define SAMP_ 256
#define SCALE_ 0.125f
#define LOG16_ 2.7725887222397811f
#define HPAD 68

typedef __attribute__((ext_vector_type(4))) float f32x4;
typedef __attribute__((ext_vector_type(8))) short bf16x8;
typedef __attribute__((ext_vector_type(4))) short bf16x4;

static __device__ __forceinline__ unsigned pack2(float a, float b) {
    union { __hip_bfloat162 h; unsigned u; } c;
    c.h = __float22bfloat162_rn(make_float2(a, b));
    return c.u;
}

static __device__ __forceinline__ bf16x8 cvt8v(f32x4 a, f32x4 b) {
    union { unsigned u[4]; bf16x8 v; } r;
    r.u[0] = pack2(a[0], a[1]); r.u[1] = pack2(a[2], a[3]);
    r.u[2] = pack2(b[0], b[1]); r.u[3] = pack2(b[2], b[3]);
    return r.v;
}

static __device__ __forceinline__ bf16x8 cvt8(const float* p) {
    return cvt8v(*(const f32x4*)p, *(const f32x4*)(p + 4));
}

// ---------------- 1. LSH hash (working) -------------------------------------
__global__ __launch_bounds__(128) void hash_kernel(
    const float* __restrict__ q, const float* __restrict__ k,
    const float* __restrict__ pd,
    unsigned char* __restrict__ qbuck, unsigned char* __restrict__ kbuck)
{
    extern __shared__ char smraw[];
    float*  Xs  = (float*)smraw;
    double* Pdl = (double*)(smraw + 128 * HPAD * 4);

    int tid = threadIdx.x;
    const float* src = blockIdx.y ? k : q;
    unsigned char* dst = blockIdx.y ? kbuck : qbuck;
    size_t tok0 = (size_t)blockIdx.x * 128;

    {
        int d = tid >> 1, r0 = (tid & 1) * 4;
#pragma unroll
        for (int j = 0; j < 4; ++j)
            Pdl[d * 8 + r0 + j] = (double)pd[d * 8 + r0 + j];
    }
    {
        const float4* src4 = (const float4*)(src + tok0 * D_);
        for (int i = tid; i < 128 * 16; i += 128) {
            int r = i >> 4, c = i & 15;
            *(float4*)&Xs[r * HPAD + c * 4] = src4[i];
        }
    }
    __syncthreads();

    float xr[64];
#pragma unroll
    for (int c = 0; c < 16; ++c)
        *(f32x4*)&xr[c * 4] = *(const f32x4*)&Xs[tid * HPAD + c * 4];

    double acc[8];
#pragma unroll
    for (int r = 0; r < 8; ++r) acc[r] = 0.0;
#pragma unroll
    for (int d = 0; d < 64; ++d) {
        double x = (double)xr[d];
        const double* pr = Pdl + d * 8;
#pragma unroll
        for (int r = 0; r < 8; ++r) acc[r] += x * pr[r];
    }
    int bin = 0;
#pragma unroll
    for (int r = 0; r < 8; ++r)
        if (acc[r] > 0.0) bin |= (1 << r);
    dst[tok0 + tid] = (unsigned char)(bin ^ (bin >> 1));
}

// ---------------- 2. stable counting sort (working) -------------------------
__global__ __launch_bounds__(256) void sort_kernel(
    const unsigned char* __restrict__ qbuck,
    const unsigned char* __restrict__ kbuck,
    int* __restrict__ q_idx, int* __restrict__ k_idx)
{
    __shared__ unsigned short hist[64][256];
    __shared__ unsigned int   binstart[256];
    __shared__ alignas(16) unsigned char bl[N_];

    int bh = blockIdx.x, tensor = blockIdx.y;
    const unsigned char* buck = (tensor ? kbuck : qbuck) + bh * N_;
    int* idx_out = (tensor ? k_idx : q_idx) + bh * N_;
    int t = threadIdx.x;

    ((uint4*)bl)[t] = ((const uint4*)buck)[t];
    {
        uint4* h4 = (uint4*)&hist[0][0];
        for (int i = t; i < 2048; i += 256) h4[i] = make_uint4(0, 0, 0, 0);
    }
    __syncthreads();

    if (t < 64) {
        for (int u = 0; u < 64; ++u) hist[t][bl[t * 64 + u]]++;
    }
    __syncthreads();

    {
        unsigned run = 0;
        for (int tt = 0; tt < 64; ++tt) {
            unsigned c = hist[tt][t];
            hist[tt][t] = (unsigned short)run;
            run += c;
        }
        binstart[t] = run;
    }
    __syncthreads();

    if (t < 64) {
        unsigned b0 = binstart[t*4], b1 = binstart[t*4+1],
                 b2 = binstart[t*4+2], b3 = binstart[t*4+3];
        unsigned s = b0 + b1 + b2 + b3, p = s;
#pragma unroll
        for (int d = 1; d < 64; d <<= 1) {
            unsigned y = __shfl_up(p, d);
            if (t >= d) p += y;
        }
        unsigned e = p - s;
        binstart[t*4]   = e;
        binstart[t*4+1] = e + b0;
        binstart[t*4+2] = e + b0 + b1;
        binstart[t*4+3] = e + b0 + b1 + b2;
    }
    __syncthreads();

    if (t < 64) {
        for (int u = 0; u < 64; ++u) {
            int tok = t * 64 + u;
            int b = bl[tok];
            int pos = (int)(binstart[b] + hist[t][b]);
            hist[t][b]++;
            idx_out[pos] = tok;
        }
    }
}

// ---------------- 3. fused attention: 64 queries per wave (mt=4) ------------
// 512 wgs x 256 thr (4 waves x 64 q = one 256-q block per wg). 4 phases of
// 128 keys (2 block + 2 sampled), 32 KB LDS. Per chunk of 32 keys the wave
// does 32 MFMAs on the same 4 K-reads + 8 tr-reads that fed 16 in R10 ->
// fixed chain latencies amortize over 2x the compute. R10's verified fence
// (lgkmcnt(0)+sched_barrier) and exp form; R10 K image; R4 V slot image.
// No min-wave launch_bound -> allocator cannot be forced to spill.
static __device__ __forceinline__ void stage_kv4(
    const float* __restrict__ key, const float* __restrict__ value,
    size_t base, int kI, int v0, int v1, int hK, int kwofs,
    int vd0, int vd1, int tid, short* Ksm, short* Vsm)
{
    {   // K: one 32-d half-row -> 4 bf16x8 writes (R10 image)
        const float* kp = key + (base + (size_t)kI) * D_ + hK * 32;
        f32x4 k0 = *(const f32x4*)kp,        k1 = *(const f32x4*)(kp + 4);
        f32x4 k2 = *(const f32x4*)(kp + 8),  k3 = *(const f32x4*)(kp + 12);
        f32x4 k4 = *(const f32x4*)(kp + 16), k5 = *(const f32x4*)(kp + 20);
        f32x4 k6 = *(const f32x4*)(kp + 24), k7 = *(const f32x4*)(kp + 28);
        *(bf16x8*)&Ksm[kwofs]       = cvt8v(k0, k1);
        *(bf16x8*)&Ksm[kwofs + 128] = cvt8v(k2, k3);
        *(bf16x8*)&Ksm[kwofs + 256] = cvt8v(k4, k5);
        *(bf16x8*)&Ksm[kwofs + 384] = cvt8v(k6, k7);
    }
    {   // V: two R4-image slots (tid and tid+256), 16 d-values each
        const float* vp0 = value + (base + (size_t)v0) * D_ + vd0;
        f32x4 a0 = *(const f32x4*)vp0, a1 = *(const f32x4*)(vp0 + 4);
        f32x4 a2 = *(const f32x4*)(vp0 + 8), a3 = *(const f32x4*)(vp0 + 12);
        *(bf16x8*)&Vsm[tid * 16]     = cvt8v(a0, a1);
        *(bf16x8*)&Vsm[tid * 16 + 8] = cvt8v(a2, a3);
        const float* vp1 = value + (base + (size_t)v1) * D_ + vd1;
        f32x4 b0 = *(const f32x4*)vp1, b1 = *(const f32x4*)(vp1 + 4);
        f32x4 b2 = *(const f32x4*)(vp1 + 8), b3 = *(const f32x4*)(vp1 + 12);
        *(bf16x8*)&Vsm[(tid + 256) * 16]     = cvt8v(b0, b1);
        *(bf16x8*)&Vsm[(tid + 256) * 16 + 8] = cvt8v(b2, b3);
    }
}

static __device__ __forceinline__ void compute_128x4(
    const short* __restrict__ Ksm, unsigned vtr, float bias,
    const bf16x8 (&qf)[4][2], int lg, int ll,
    f32x4 (&o)[4][4], float (&lsum)[4])
{
#pragma unroll
    for (int c = 0; c < 4; ++c) {
        unsigned pbu[4][4];
        __builtin_amdgcn_s_setprio(1);
#pragma unroll
        for (int t = 0; t < 2; ++t) {
            int kt = c * 2 + t;
            f32x4 s[4];
#pragma unroll
            for (int mt = 0; mt < 4; ++mt) { f32x4 z = {0.f,0.f,0.f,0.f}; s[mt] = z; }
#pragma unroll
            for (int ks = 0; ks < 2; ++ks) {
                bf16x8 a = *(const bf16x8*)&Ksm[kt * 1024 + ks * 512 + lg * 128 + ll * 8];
#pragma unroll
                for (int mt = 0; mt < 4; ++mt)
                    s[mt] = __builtin_amdgcn_mfma_f32_16x16x32_bf16(a, qf[mt][ks], s[mt], 0, 0, 0);
            }
            __builtin_amdgcn_s_setprio(0);
#pragma unroll
            for (int mt = 0; mt < 4; ++mt) {
                f32x4 e;
#pragma unroll
                for (int r = 0; r < 4; ++r)
                    e[r] = __expf(fmaf(s[mt][r], SCALE_, bias));
                lsum[mt] += (e[0] + e[1]) + (e[2] + e[3]);
                pbu[mt][t*2]   = pack2(e[0], e[1]);
                pbu[mt][t*2+1] = pack2(e[2], e[3]);
            }
            __builtin_amdgcn_s_setprio(1);
        }
        bf16x8 pb[4];
#pragma unroll
        for (int mt = 0; mt < 4; ++mt) {
            union { unsigned u[4]; bf16x8 v; } cc;
            cc.u[0]=pbu[mt][0]; cc.u[1]=pbu[mt][1];
            cc.u[2]=pbu[mt][2]; cc.u[3]=pbu[mt][3];
            pb[mt] = cc.v;
        }

        bf16x4 tr[4][2];
#pragma unroll
        for (int dt = 0; dt < 4; ++dt) {
            asm volatile("ds_read_b64_tr_b16 %0, %1 offset:%2"
                         : "=v"(tr[dt][0]) : "v"(vtr), "i"(c * 4096 + dt * 128));
            asm volatile("ds_read_b64_tr_b16 %0, %1 offset:%2"
                         : "=v"(tr[dt][1]) : "v"(vtr), "i"(c * 4096 + dt * 128 + 2048));
        }
        asm volatile("s_waitcnt lgkmcnt(0)" ::: "memory");
        __builtin_amdgcn_sched_barrier(0);
#pragma unroll
        for (int dt = 0; dt < 4; ++dt) {
            union { bf16x4 h[2]; bf16x8 v; } va;
            va.h[0] = tr[dt][0]; va.h[1] = tr[dt][1];
#pragma unroll
            for (int mt = 0; mt < 4; ++mt)
                o[dt][mt] = __builtin_amdgcn_mfma_f32_16x16x32_bf16(va.v, pb[mt], o[dt][mt], 0, 0, 0);
        }
        __builtin_amdgcn_s_setprio(0);
    }
}

__global__ __launch_bounds__(256) void fused_attn(
    const float* __restrict__ query, const float* __restrict__ key,
    const float* __restrict__ value, const int* __restrict__ q_idx,
    const int* __restrict__ k_idx, const int* __restrict__ sampled,
    float* __restrict__ out)
{
    __shared__ __align__(16) short Ksm[8192];   // 16 KB (128 keys x 64 d)
    __shared__ __align__(16) short Vsm[8192];   // 16 KB
    int wgid = blockIdx.x;
    int wg = (wgid & 7) * 64 + (wgid >> 3);     // bijective XCD swizzle (512)
    int bh = wg >> 4, blk = wg & 15;
    int tid = threadIdx.x, w = tid >> 6, l = tid & 63, lg = l >> 4, ll = l & 15;
    size_t base = (size_t)bh * N_;

    const int* kidxA = k_idx + base + blk * 256;
    const int* kidxB = sampled + bh * SAMP_;

    // staging decompositions
    int rK = tid & 127, hK = tid >> 7;
    int kwofs = (rK >> 4) * 1024 + hK * 512 + (rK & 15) * 8;
    int vj0 = ((tid >> 4) << 2) | (tid & 3);
    int vd0 = ((tid >> 2) & 3) * 16;
    int s1  = tid + 256;
    int vj1 = ((s1 >> 4) << 2) | (s1 & 3);
    int vd1 = ((s1 >> 2) & 3) * 16;

    // Q fragments: wave owns 64 queries (mt = 0..3)
    const int* qidx = q_idx + base + blk * 256 + w * 64;
    int qr[4]; bf16x8 qf[4][2];
#pragma unroll
    for (int mt = 0; mt < 4; ++mt) {
        qr[mt] = qidx[mt * 16 + ll];
        const float* qp = query + (base + (size_t)qr[mt]) * D_;
#pragma unroll
        for (int ks = 0; ks < 2; ++ks)
            qf[mt][ks] = cvt8(qp + ks * 32 + lg * 8);
    }

    f32x4 o[4][4]; float lsum[4];
#pragma unroll
    for (int mt = 0; mt < 4; ++mt) {
        lsum[mt] = 0.f;
#pragma unroll
        for (int dt = 0; dt < 4; ++dt) { f32x4 z = {0.f,0.f,0.f,0.f}; o[dt][mt] = z; }
    }
    unsigned vtr = (unsigned)(unsigned long long)(void*)&Vsm[0] + lg * 512 + ll * 8;

    // ---- phase 0: block keys 0..127
    int kI = kidxA[rK], v0 = kidxA[vj0], v1 = kidxA[vj1];
    stage_kv4(key, value, base, kI, v0, v1, hK, kwofs, vd0, vd1, tid, Ksm, Vsm);
    __syncthreads();
    kI = kidxA[128 + rK]; v0 = kidxA[128 + vj0]; v1 = kidxA[128 + vj1];
    compute_128x4(Ksm, vtr, 0.f, qf, lg, ll, o, lsum);
    __syncthreads();

    // ---- phase 1: block keys 128..255
    stage_kv4(key, value, base, kI, v0, v1, hK, kwofs, vd0, vd1, tid, Ksm, Vsm);
    __syncthreads();
    kI = kidxB[rK]; v0 = kidxB[vj0]; v1 = kidxB[vj1];
    compute_128x4(Ksm, vtr, 0.f, qf, lg, ll, o, lsum);
    __syncthreads();

    // ---- phase 2: sampled keys 0..127 (residual weight 16 in exp bias)
    stage_kv4(key, value, base, kI, v0, v1, hK, kwofs, vd0, vd1, tid, Ksm, Vsm);
    __syncthreads();
    kI = kidxB[128 + rK]; v0 = kidxB[128 + vj0]; v1 = kidxB[128 + vj1];
    compute_128x4(Ksm, vtr, LOG16_, qf, lg, ll, o, lsum);
    __syncthreads();

    // ---- phase 3: sampled keys 128..255
    stage_kv4(key, value, base, kI, v0, v1, hK, kwofs, vd0, vd1, tid, Ksm, Vsm);
    __syncthreads();
    compute_128x4(Ksm, vtr, LOG16_, qf, lg, ll, o, lsum);

    // ---- row-sum over lg groups; epilogue out = o / l
#pragma unroll
    for (int mt = 0; mt < 4; ++mt) {
        float v = lsum[mt];
        v += __shfl_xor(v, 16);
        v += __shfl_xor(v, 32);
        lsum[mt] = v;
    }
#pragma unroll
    for (int mt = 0; mt < 4; ++mt) {
        float dn = 1.f / lsum[mt];
        float* orow = out + (base + (size_t)qr[mt]) * D_ + lg * 4;
#pragma unroll
        for (int dt = 0; dt < 4; ++dt) {
            f32x4 v = o[dt][mt] * dn;
            *(f32x4*)&orow[dt * 16] = v;
        }
    }
}

// ---------------------------------------------------------------------------
extern "C" void kernel_launch(void* const* d_in, const int* in_sizes, int n_in,
                              void* d_out, int out_size, void* d_ws, size_t ws_size,
                              hipStream_t stream)
{
    const float* query = (const float*)d_in[0];
    const float* key   = (const float*)d_in[1];
    const float* value = (const float*)d_in[2];
    const float* pd    = (const float*)d_in[3];
    const int*   samp  = (const int*)d_in[4];
    float* out = (float*)d_out;

    char* ws = (char*)d_ws;
    unsigned char* qbuck = (unsigned char*)ws;                 // 128 KB
    unsigned char* kbuck = qbuck + (size_t)BH_ * N_;           // 128 KB
    int* q_idx = (int*)(ws + 262144);                          // 512 KB
    int* k_idx = (int*)(ws + 262144 + 524288);                 // 512 KB

    size_t hash_lds = 128 * HPAD * 4 + 512 * 8;
    hipLaunchKernelGGL(hash_kernel, dim3(BH_ * N_ / 128, 2), dim3(128),
                       hash_lds, stream, query, key, pd, qbuck, kbuck);
    hipLaunchKernelGGL(sort_kernel, dim3(BH_, 2), dim3(256), 0, stream,
                       qbuck, kbuck, q_idx, k_idx);
    hipLaunchKernelGGL(fused_attn, dim3(512), dim3(256), 0, stream,
                       query, key, value, q_idx, k_idx, samp, out);
}

// Round 17
// 79.903 us; speedup vs baseline: 1.0311x; 1.0311x over previous
//
#include <hip/hip_runtime.h>
#include <hip/hip_bf16.h>
#include <math.h>

#define BH_ 32
#define N_ 4096
#define D_ 64
#define SAMP_ 256
#define SCALE_ 0.125f
#define LOG16_ 2.7725887222397811f
#define HPAD 68

typedef __attribute__((ext_vector_type(4))) float f32x4;
typedef __attribute__((ext_vector_type(8))) short bf16x8;
typedef __attribute__((ext_vector_type(4))) short bf16x4;

static __device__ __forceinline__ unsigned pack2(float a, float b) {
    union { __hip_bfloat162 h; unsigned u; } c;
    c.h = __float22bfloat162_rn(make_float2(a, b));
    return c.u;
}

static __device__ __forceinline__ bf16x8 cvt8v(f32x4 a, f32x4 b) {
    union { unsigned u[4]; bf16x8 v; } r;
    r.u[0] = pack2(a[0], a[1]); r.u[1] = pack2(a[2], a[3]);
    r.u[2] = pack2(b[0], b[1]); r.u[3] = pack2(b[2], b[3]);
    return r.v;
}

static __device__ __forceinline__ bf16x8 cvt8(const float* p) {
    return cvt8v(*(const f32x4*)p, *(const f32x4*)(p + 4));
}

// ---------------- 1. LSH hash (working) -------------------------------------
__global__ __launch_bounds__(128) void hash_kernel(
    const float* __restrict__ q, const float* __restrict__ k,
    const float* __restrict__ pd,
    unsigned char* __restrict__ qbuck, unsigned char* __restrict__ kbuck)
{
    extern __shared__ char smraw[];
    float*  Xs  = (float*)smraw;
    double* Pdl = (double*)(smraw + 128 * HPAD * 4);

    int tid = threadIdx.x;
    const float* src = blockIdx.y ? k : q;
    unsigned char* dst = blockIdx.y ? kbuck : qbuck;
    size_t tok0 = (size_t)blockIdx.x * 128;

    {
        int d = tid >> 1, r0 = (tid & 1) * 4;
#pragma unroll
        for (int j = 0; j < 4; ++j)
            Pdl[d * 8 + r0 + j] = (double)pd[d * 8 + r0 + j];
    }
    {
        const float4* src4 = (const float4*)(src + tok0 * D_);
        for (int i = tid; i < 128 * 16; i += 128) {
            int r = i >> 4, c = i & 15;
            *(float4*)&Xs[r * HPAD + c * 4] = src4[i];
        }
    }
    __syncthreads();

    float xr[64];
#pragma unroll
    for (int c = 0; c < 16; ++c)
        *(f32x4*)&xr[c * 4] = *(const f32x4*)&Xs[tid * HPAD + c * 4];

    double acc[8];
#pragma unroll
    for (int r = 0; r < 8; ++r) acc[r] = 0.0;
#pragma unroll
    for (int d = 0; d < 64; ++d) {
        double x = (double)xr[d];
        const double* pr = Pdl + d * 8;
#pragma unroll
        for (int r = 0; r < 8; ++r) acc[r] += x * pr[r];
    }
    int bin = 0;
#pragma unroll
    for (int r = 0; r < 8; ++r)
        if (acc[r] > 0.0) bin |= (1 << r);
    dst[tok0 + tid] = (unsigned char)(bin ^ (bin >> 1));
}

// ---------------- 2. stable counting sort (working) -------------------------
__global__ __launch_bounds__(256) void sort_kernel(
    const unsigned char* __restrict__ qbuck,
    const unsigned char* __restrict__ kbuck,
    int* __restrict__ q_idx, int* __restrict__ k_idx)
{
    __shared__ unsigned short hist[64][256];
    __shared__ unsigned int   binstart[256];
    __shared__ alignas(16) unsigned char bl[N_];

    int bh = blockIdx.x, tensor = blockIdx.y;
    const unsigned char* buck = (tensor ? kbuck : qbuck) + bh * N_;
    int* idx_out = (tensor ? k_idx : q_idx) + bh * N_;
    int t = threadIdx.x;

    ((uint4*)bl)[t] = ((const uint4*)buck)[t];
    {
        uint4* h4 = (uint4*)&hist[0][0];
        for (int i = t; i < 2048; i += 256) h4[i] = make_uint4(0, 0, 0, 0);
    }
    __syncthreads();

    if (t < 64) {
        for (int u = 0; u < 64; ++u) hist[t][bl[t * 64 + u]]++;
    }
    __syncthreads();

    {
        unsigned run = 0;
        for (int tt = 0; tt < 64; ++tt) {
            unsigned c = hist[tt][t];
            hist[tt][t] = (unsigned short)run;
            run += c;
        }
        binstart[t] = run;
    }
    __syncthreads();

    if (t < 64) {
        unsigned b0 = binstart[t*4], b1 = binstart[t*4+1],
                 b2 = binstart[t*4+2], b3 = binstart[t*4+3];
        unsigned s = b0 + b1 + b2 + b3, p = s;
#pragma unroll
        for (int d = 1; d < 64; d <<= 1) {
            unsigned y = __shfl_up(p, d);
            if (t >= d) p += y;
        }
        unsigned e = p - s;
        binstart[t*4]   = e;
        binstart[t*4+1] = e + b0;
        binstart[t*4+2] = e + b0 + b1;
        binstart[t*4+3] = e + b0 + b1 + b2;
    }
    __syncthreads();

    if (t < 64) {
        for (int u = 0; u < 64; ++u) {
            int tok = t * 64 + u;
            int b = bl[tok];
            int pos = (int)(binstart[b] + hist[t][b]);
            hist[t][b]++;
            idx_out[pos] = tok;
        }
    }
}

// ---------------- 3. fused attention: 2-deep pipelined chunks ---------------
// R10 structure (60 VGPR, no spill, 59us) with the compute region rewritten
// as a 2-deep software pipeline that exploits IN-ORDER lgkm completion:
// tr-reads(c) are issued at the end of iter c-1; iter c runs QKexp(c+1)
// FIRST -- the compiler's own wait for its K ds_read_b128s (issued after the
// trs) implicitly completes tr(c), so the explicit fence before PV(c) is
// ~free, and PV(c) overlaps with the next chunk's score pipeline.
static __device__ __forceinline__ void stage_kv(
    const float* __restrict__ key, const float* __restrict__ value,
    size_t base, int krI, int v0, int v1, int v2, int v3,
    int hK, int kwofs, int vd, int tid, short* Ksm, short* Vsm)
{
    {
        const float* kp = key + (base + (size_t)krI) * D_ + hK * 32;
        f32x4 k0 = *(const f32x4*)kp,        k1 = *(const f32x4*)(kp + 4);
        f32x4 k2 = *(const f32x4*)(kp + 8),  k3 = *(const f32x4*)(kp + 12);
        f32x4 k4 = *(const f32x4*)(kp + 16), k5 = *(const f32x4*)(kp + 20);
        f32x4 k6 = *(const f32x4*)(kp + 24), k7 = *(const f32x4*)(kp + 28);
        *(bf16x8*)&Ksm[kwofs]       = cvt8v(k0, k1);
        *(bf16x8*)&Ksm[kwofs + 128] = cvt8v(k2, k3);
        *(bf16x8*)&Ksm[kwofs + 256] = cvt8v(k4, k5);
        *(bf16x8*)&Ksm[kwofs + 384] = cvt8v(k6, k7);
    }
    {
        const float* vp0 = value + (base + (size_t)v0) * D_ + vd;
        const float* vp1 = value + (base + (size_t)v1) * D_ + vd;
        const float* vp2 = value + (base + (size_t)v2) * D_ + vd;
        const float* vp3 = value + (base + (size_t)v3) * D_ + vd;
        f32x4 a0 = *(const f32x4*)vp0, b0 = *(const f32x4*)(vp0 + 4);
        f32x4 a1 = *(const f32x4*)vp1, b1 = *(const f32x4*)(vp1 + 4);
        f32x4 a2 = *(const f32x4*)vp2, b2 = *(const f32x4*)(vp2 + 4);
        f32x4 a3 = *(const f32x4*)vp3, b3 = *(const f32x4*)(vp3 + 4);
        *(bf16x8*)&Vsm[tid * 8]         = cvt8v(a0, b0);
        *(bf16x8*)&Vsm[4096 + tid * 8]  = cvt8v(a1, b1);
        *(bf16x8*)&Vsm[8192 + tid * 8]  = cvt8v(a2, b2);
        *(bf16x8*)&Vsm[12288 + tid * 8] = cvt8v(a3, b3);
    }
}

// QK^T + softmax for one chunk (2 kt-tiles); produces packed P fragments.
static __device__ __forceinline__ void qkexp(
    const short* __restrict__ Ksm, int hgi, float bias,
    const bf16x8 (&qf)[2][2], int lg, int ll,
    float (&lsum)[2], bf16x8& pb0, bf16x8& pb1)
{
    unsigned pbu[2][4];
#pragma unroll
    for (int t = 0; t < 2; ++t) {
        int kt = hgi * 2 + t;
        f32x4 s0 = {0.f,0.f,0.f,0.f}, s1 = {0.f,0.f,0.f,0.f};
#pragma unroll
        for (int ks = 0; ks < 2; ++ks) {
            bf16x8 a = *(const bf16x8*)&Ksm[kt * 1024 + ks * 512 + lg * 128 + ll * 8];
            s0 = __builtin_amdgcn_mfma_f32_16x16x32_bf16(a, qf[0][ks], s0, 0, 0, 0);
            s1 = __builtin_amdgcn_mfma_f32_16x16x32_bf16(a, qf[1][ks], s1, 0, 0, 0);
        }
        f32x4 e0, e1;
#pragma unroll
        for (int r = 0; r < 4; ++r) {
            e0[r] = __expf(fmaf(s0[r], SCALE_, bias));
            e1[r] = __expf(fmaf(s1[r], SCALE_, bias));
        }
        lsum[0] += (e0[0] + e0[1]) + (e0[2] + e0[3]);
        lsum[1] += (e1[0] + e1[1]) + (e1[2] + e1[3]);
        pbu[0][t*2]   = pack2(e0[0], e0[1]);
        pbu[0][t*2+1] = pack2(e0[2], e0[3]);
        pbu[1][t*2]   = pack2(e1[0], e1[1]);
        pbu[1][t*2+1] = pack2(e1[2], e1[3]);
    }
    { union { unsigned u[4]; bf16x8 v; } cc;
      cc.u[0]=pbu[0][0]; cc.u[1]=pbu[0][1]; cc.u[2]=pbu[0][2]; cc.u[3]=pbu[0][3]; pb0=cc.v; }
    { union { unsigned u[4]; bf16x8 v; } cc;
      cc.u[0]=pbu[1][0]; cc.u[1]=pbu[1][1]; cc.u[2]=pbu[1][2]; cc.u[3]=pbu[1][3]; pb1=cc.v; }
}

#define TR_ISSUE_(C) do { \
    _Pragma("unroll") \
    for (int dt = 0; dt < 4; ++dt) { \
        asm volatile("ds_read_b64_tr_b16 %0, %1 offset:%2" \
                     : "=v"(tr[dt][0]) : "v"(vtr0), "i"((C) * 4096 + dt * 128)); \
        asm volatile("ds_read_b64_tr_b16 %0, %1 offset:%2" \
                     : "=v"(tr[dt][1]) : "v"(vtr0), "i"((C) * 4096 + dt * 128 + 2048)); \
    } } while (0)

static __device__ __forceinline__ void compute_256(
    const short* __restrict__ Ksm, unsigned vtr0, float bias,
    const bf16x8 (&qf)[2][2], int lg, int ll,
    f32x4 (&o)[4][2], float (&lsum)[2])
{
    bf16x8 pb0, pb1, pn0, pn1;
    bf16x4 tr[4][2];

    __builtin_amdgcn_s_setprio(1);
    // prologue: scores(0) + tr-issue(0)
    qkexp(Ksm, 0, bias, qf, lg, ll, lsum, pb0, pb1);
    TR_ISSUE_(0);

#pragma unroll
    for (int c = 0; c < 8; ++c) {
        // scores for chunk c+1 FIRST: its K ds_read waits (compiler-emitted,
        // conservative lgkmcnt) drain the older tr(c) reads for free.
        if (c < 7)
            qkexp(Ksm, c + 1, bias, qf, lg, ll, lsum, pn0, pn1);

        // fence before consuming tr(c) (rule #18); cheap in steady state
        asm volatile("s_waitcnt lgkmcnt(0)" ::: "memory");
        __builtin_amdgcn_sched_barrier(0);

        // PV(c)
#pragma unroll
        for (int dt = 0; dt < 4; ++dt) {
            union { bf16x4 h[2]; bf16x8 v; } va;
            va.h[0] = tr[dt][0]; va.h[1] = tr[dt][1];
            o[dt][0] = __builtin_amdgcn_mfma_f32_16x16x32_bf16(va.v, pb0, o[dt][0], 0, 0, 0);
            o[dt][1] = __builtin_amdgcn_mfma_f32_16x16x32_bf16(va.v, pb1, o[dt][1], 0, 0, 0);
        }

        if (c < 7) {
            TR_ISSUE_(c + 1);      // latency hides under next iter's K-waits
            pb0 = pn0; pb1 = pn1;
        }
    }
    __builtin_amdgcn_s_setprio(0);
}

__global__ __launch_bounds__(512, 4) void fused_attn(
    const float* __restrict__ query, const float* __restrict__ key,
    const float* __restrict__ value, const int* __restrict__ q_idx,
    const int* __restrict__ k_idx, const int* __restrict__ sampled,
    float* __restrict__ out)
{
    __shared__ __align__(16) short Ksm[16384];   // 32 KB
    __shared__ __align__(16) short Vsm[16384];   // 32 KB
    int wgid = blockIdx.x;
    int wg = (wgid & 7) * 64 + (wgid >> 3);      // bijective XCD swizzle
    int bh = wg >> 4, blk = wg & 15;
    int tid = threadIdx.x, w = tid >> 6, l = tid & 63, lg = l >> 4, ll = l & 15;
    size_t base = (size_t)bh * N_;

    const int* kidxA = k_idx + base + blk * 256;
    const int* kidxB = sampled + bh * SAMP_;

    // staging decomposition
    int rK = tid & 255, hK = tid >> 8;
    int kwofs = (rK >> 4) * 1024 + hK * 512 + (rK & 15) * 8;
    int l6 = tid & 63, i6 = tid >> 6;
    int vrow = (i6 >> 2) * 32 + (l6 >> 5) * 4 + ((l6 >> 1) & 3) + (i6 & 3) * 8;
    int vd   = (((l6 >> 3) & 3) * 2 + (l6 & 1)) * 8;

    // phase A indices
    int krA = kidxA[rK];
    int vA0 = kidxA[vrow],       vA1 = kidxA[64 + vrow];
    int vA2 = kidxA[128 + vrow], vA3 = kidxA[192 + vrow];

    // Q fragments (wave owns 32 queries)
    const int* qidx = q_idx + base + blk * 256 + w * 32;
    int qr[2]; bf16x8 qf[2][2];
#pragma unroll
    for (int mt = 0; mt < 2; ++mt) {
        qr[mt] = qidx[mt * 16 + ll];
        const float* qp = query + (base + (size_t)qr[mt]) * D_;
#pragma unroll
        for (int ks = 0; ks < 2; ++ks)
            qf[mt][ks] = cvt8(qp + ks * 32 + lg * 8);
    }

    f32x4 o[4][2]; float lsum[2];
#pragma unroll
    for (int mt = 0; mt < 2; ++mt) {
        lsum[mt] = 0.f;
#pragma unroll
        for (int dt = 0; dt < 4; ++dt) { f32x4 z = {0.f,0.f,0.f,0.f}; o[dt][mt] = z; }
    }
    unsigned vtr0 = (unsigned)(unsigned long long)(void*)&Vsm[0] + lg * 512 + ll * 8;

    // ---- phase A: stage, sync, compute (B indices prefetched under compute)
    stage_kv(key, value, base, krA, vA0, vA1, vA2, vA3, hK, kwofs, vd, tid, Ksm, Vsm);
    __syncthreads();

    int krB = kidxB[rK];
    int vB0 = kidxB[vrow],       vB1 = kidxB[64 + vrow];
    int vB2 = kidxB[128 + vrow], vB3 = kidxB[192 + vrow];

    compute_256(Ksm, vtr0, 0.f, qf, lg, ll, o, lsum);
    __syncthreads();

    // ---- phase B
    stage_kv(key, value, base, krB, vB0, vB1, vB2, vB3, hK, kwofs, vd, tid, Ksm, Vsm);
    __syncthreads();
    compute_256(Ksm, vtr0, LOG16_, qf, lg, ll, o, lsum);

    // ---- row-sum over lg groups; epilogue out = o / l
#pragma unroll
    for (int mt = 0; mt < 2; ++mt) {
        float v = lsum[mt];
        v += __shfl_xor(v, 16);
        v += __shfl_xor(v, 32);
        lsum[mt] = v;
    }
#pragma unroll
    for (int mt = 0; mt < 2; ++mt) {
        float dn = 1.f / lsum[mt];
        float* orow = out + (base + (size_t)qr[mt]) * D_ + lg * 4;
#pragma unroll
        for (int dt = 0; dt < 4; ++dt) {
            f32x4 v = o[dt][mt] * dn;
            *(f32x4*)&orow[dt * 16] = v;
        }
    }
}

// ---------------------------------------------------------------------------
extern "C" void kernel_launch(void* const* d_in, const int* in_sizes, int n_in,
                              void* d_out, int out_size, void* d_ws, size_t ws_size,
                              hipStream_t stream)
{
    const float* query = (const float*)d_in[0];
    const float* key   = (const float*)d_in[1];
    const float* value = (const float*)d_in[2];
    const float* pd    = (const float*)d_in[3];
    const int*   samp  = (const int*)d_in[4];
    float* out = (float*)d_out;

    char* ws = (char*)d_ws;
    unsigned char* qbuck = (unsigned char*)ws;                 // 128 KB
    unsigned char* kbuck = qbuck + (size_t)BH_ * N_;           // 128 KB
    int* q_idx = (int*)(ws + 262144);                          // 512 KB
    int* k_idx = (int*)(ws + 262144 + 524288);                 // 512 KB

    size_t hash_lds = 128 * HPAD * 4 + 512 * 8;
    hipLaunchKernelGGL(hash_kernel, dim3(BH_ * N_ / 128, 2), dim3(128),
                       hash_lds, stream, query, key, pd, qbuck, kbuck);
    hipLaunchKernelGGL(sort_kernel, dim3(BH_, 2), dim3(256), 0, stream,
                       qbuck, kbuck, q_idx, k_idx);
    hipLaunchKernelGGL(fused_attn, dim3(512), dim3(512), 0, stream,
                       query, key, value, q_idx, k_idx, samp, out);
}